// Round 4
// baseline (178.567 us; speedup 1.0000x reference)
//
#include <hip/hip_runtime.h>

typedef __attribute__((ext_vector_type(8))) short bf16x8;
typedef __attribute__((ext_vector_type(4))) float floatx4;

__device__ __forceinline__ unsigned short f2bf(float f) {
    unsigned int u = __float_as_uint(f);
    u += 0x7FFFu + ((u >> 16) & 1u);
    return (unsigned short)(u >> 16);
}

__device__ __forceinline__ int interp_word(int a00, int a01, int a10, int a11,
                                           float w00, float w01, float w10, float w11) {
    float vl = w00 * __uint_as_float((unsigned)a00 << 16)
             + w01 * __uint_as_float((unsigned)a01 << 16)
             + w10 * __uint_as_float((unsigned)a10 << 16)
             + w11 * __uint_as_float((unsigned)a11 << 16);
    float vh = w00 * __uint_as_float((unsigned)a00 & 0xffff0000u)
             + w01 * __uint_as_float((unsigned)a01 & 0xffff0000u)
             + w10 * __uint_as_float((unsigned)a10 & 0xffff0000u)
             + w11 * __uint_as_float((unsigned)a11 & 0xffff0000u);
    return (int)__builtin_amdgcn_perm(__float_as_uint(vh) + 0x8000u,
                                      __float_as_uint(vl) + 0x8000u, 0x07060302u);
}

// ---- prep: [0,1024) x->NHWC bf16 | [1024,1312) Wk frag-major | [1312,1384) Woff frag-major ----
// Fragment-major: elem (tap, tile=mt*2+kc, lane, j) at flat [tap*T + tile*512 + lane*8 + j],
// holding W[row = mt*16 + (lane&15)][k = kc*32 + (lane>>4)*8 + j] for that tap.
__global__ __launch_bounds__(256) void prep_all(const float* __restrict__ x,
        const float* __restrict__ Wk, const float* __restrict__ Woff,
        unsigned short* __restrict__ xt, unsigned short* __restrict__ Wkb2,
        unsigned short* __restrict__ Woffb) {
    int bb = blockIdx.x;
    if (bb < 1024) {
        __shared__ float tile[64][65];
        int b = bb >> 6, y = bb & 63;
        const float* src = x + (size_t)b * 262144 + y * 64;   // + c*4096 + xc
        int tx = threadIdx.x & 15, tg = threadIdx.x >> 4;
#pragma unroll
        for (int i = 0; i < 4; i++) {
            int c = tg + i * 16;
            float4 v = *(const float4*)(src + (size_t)c * 4096 + tx * 4);
            tile[c][tx * 4 + 0] = v.x; tile[c][tx * 4 + 1] = v.y;
            tile[c][tx * 4 + 2] = v.z; tile[c][tx * 4 + 3] = v.w;
        }
        __syncthreads();
        unsigned short* dst = xt + (size_t)bb * 4096;   // [xc][c] bf16
#pragma unroll
        for (int i = 0; i < 4; i++) {
            int xc = tg + i * 16;
            int c4 = tx * 4;
            ushort4 v;
            v.x = f2bf(tile[c4 + 0][xc]); v.y = f2bf(tile[c4 + 1][xc]);
            v.z = f2bf(tile[c4 + 2][xc]); v.w = f2bf(tile[c4 + 3][xc]);
            *(ushort4*)(dst + xc * 64 + c4) = v;
        }
    } else if (bb < 1312) {
        int idx = (bb - 1024) * 256 + threadIdx.x;      // [0, 73728): 9 taps x 16 tiles x 512
        int tap = idx >> 13;
        int r = idx & 8191;
        int tile = r >> 9;
        int ln = (r >> 3) & 63;
        int j = r & 7;
        int mt = tile >> 1, kc = tile & 1;
        int oc = mt * 16 + (ln & 15);
        int c = kc * 32 + (ln >> 4) * 8 + j;
        Wkb2[idx] = f2bf(Wk[(oc * 64 + c) * 9 + tap]);
    } else {
        int idx = (bb - 1312) * 256 + threadIdx.x;      // [0, 18432): 9 taps x 4 tiles x 512
        int tap = idx >> 11;
        int r = idx & 2047;
        int tile = r >> 9;
        int ln = (r >> 3) & 63;
        int j = r & 7;
        int mt = tile >> 1, kc = tile & 1;
        int n = mt * 16 + (ln & 15);
        int c = kc * 32 + (ln >> 4) * 8 + j;
        float v = (n < 18) ? Woff[(n * 64 + c) * 9 + tap] : 0.f;
        Woffb[idx] = f2bf(v);
    }
}

// ---- fused kernel, 1-wave blocks (64 thr, grid 4096): fully barrier-free, each wave
//      self-contained (16 px, all 128 oc). Pipeline pinned with sched_barrier(0):
//      per tap, issue ALL 16 A-frag loads, then next-tap's 8 gathers, THEN pin;
//      MFMA vmcnt waits land on the A-frags (older than the gathers), so the young
//      gathers stay in flight across the whole interp+MFMA window.
//      launch_bounds(64,3): VGPR cap ~168 -> 3 waves/SIMD residency. ----
__global__ __launch_bounds__(64, 3) void fused_kernel(
        const unsigned short* __restrict__ xt,     // [b][y][x][c] bf16
        const unsigned short* __restrict__ Wkb2,   // frag-major, 9*8192
        const unsigned short* __restrict__ Woffb,  // frag-major, 9*2048
        const float* __restrict__ boff,
        const float* __restrict__ bias,
        float* __restrict__ out) {
    __shared__ float offs[16][20];                 // 1.25 KB, wave-private
    int lane = threadIdx.x;
    int frow = lane & 15, quad = lane >> 4;
    // XCD-aware remap: 2 whole batch images per XCD
    int bb = blockIdx.x;
    int xcd = bb & 7, idx = bb >> 3;               // idx in [0,512)
    int b = xcd * 2 + (idx >> 8);
    int pxBase = (idx & 255) * 16;
    int px = pxBase + frow;
    int y = px >> 6, xx = px & 63;
    const char* img = (const char*)(xt + (size_t)b * 262144) + quad * 16;

    // boff values this lane will need for its offs-write (loads overlap GEMM1)
    float bv[2][4];
#pragma unroll
    for (int mt = 0; mt < 2; mt++)
#pragma unroll
        for (int rg = 0; rg < 4; rg++) {
            int n = mt * 16 + quad * 4 + rg;
            bv[mt][rg] = (n < 18) ? boff[n] : 0.f;
        }

    // ================= GEMM1: offset conv (zero-padded taps) =================
    floatx4 acc1[2];
    acc1[0] = (floatx4)(0.f); acc1[1] = (floatx4)(0.f);
#pragma unroll
    for (int tap = 0; tap < 9; tap++) {
        int ry = y + tap / 3 - 1, rx = xx + tap % 3 - 1;
        bool valid = (ry >= 0) & (ry < 64) & (rx >= 0) & (rx < 64);
        const char* src = img + ((ry * 64 + rx) << 7);
        const unsigned short* wofft = Woffb + tap * 2048 + lane * 8;
        bf16x8 bz = {};
#pragma unroll
        for (int kc = 0; kc < 2; kc++) {
            bf16x8 bfr = valid ? *(const bf16x8*)(src + kc * 64) : bz;
#pragma unroll
            for (int mt = 0; mt < 2; mt++) {
                bf16x8 af = *(const bf16x8*)(wofft + (mt * 2 + kc) * 512);
                acc1[mt] = __builtin_amdgcn_mfma_f32_16x16x32_bf16(af, bfr, acc1[mt], 0, 0, 0);
            }
        }
    }
    // D: col=frow(px), row=quad*4+rg (+mt*16) -> offset channel n of pixel frow.
    // Single wave: ds_write -> ds_read ordering handled by lgkmcnt, no barrier.
#pragma unroll
    for (int mt = 0; mt < 2; mt++)
#pragma unroll
        for (int rg = 0; rg < 4; rg++) {
            int n = mt * 16 + quad * 4 + rg;
            if (n < 18) offs[frow][n] = acc1[mt][rg] + bv[mt][rg];
        }

    // ================= GEMM2: bilinear sample + main conv, software-pipelined ========
    floatx4 acc[8];
#pragma unroll
    for (int i = 0; i < 8; i++) acc[i] = (floatx4)(0.f);

    const float* op = &offs[frow][0];

    // stage(tap): compute bilinear weights + issue the 8 scattered corner loads
    auto stage = [&](int tap, int4 (&r00)[2], int4 (&r01)[2], int4 (&r10)[2],
                     int4 (&r11)[2], floatx4& w) {
        float orow = op[tap];
        float ocol = op[9 + tap];
        float pr = (float)(y + tap / 3 - 1) + orow;
        float pc = (float)(xx + tap % 3 - 1) + ocol;
        pr = fminf(fmaxf(pr, 0.f), 63.f);
        pc = fminf(fmaxf(pc, 0.f), 63.f);
        float fr = floorf(pr), fc = floorf(pc);
        float tr = pr - fr, tc = pc - fc;
        int r0 = (int)fr, c0 = (int)fc;
        int r1 = min(r0 + 1, 63), c1 = min(c0 + 1, 63);
        w[0] = (1.f - tr) * (1.f - tc);
        w[1] = (1.f - tr) * tc;
        w[2] = tr * (1.f - tc);
        w[3] = tr * tc;
        const char* p00 = img + ((r0 * 64 + c0) << 7);
        const char* p01 = img + ((r0 * 64 + c1) << 7);
        const char* p10 = img + ((r1 * 64 + c0) << 7);
        const char* p11 = img + ((r1 * 64 + c1) << 7);
#pragma unroll
        for (int kc = 0; kc < 2; kc++) {
            r00[kc] = *(const int4*)(p00 + kc * 64);
            r01[kc] = *(const int4*)(p01 + kc * 64);
            r10[kc] = *(const int4*)(p10 + kc * 64);
            r11[kc] = *(const int4*)(p11 + kc * 64);
        }
    };

    int4 c00[2], c01[2], c10[2], c11[2];
    floatx4 cw;
    stage(0, c00, c01, c10, c11, cw);

#pragma unroll 1
    for (int tap = 0; tap < 9; tap++) {
        const unsigned short* wkt = Wkb2 + tap * 8192 + lane * 8;

        // (1) ALL 16 A-frag loads first (L1-hot, contiguous). They are OLDER than
        //     the gathers below, so MFMA vmcnt waits never drain the gathers.
        bf16x8 af[16];
#pragma unroll
        for (int t = 0; t < 16; t++)
            af[t] = *(const bf16x8*)(wkt + t * 512);

        // (2) issue tap t+1's 8 scattered gathers into the second register set
        int4 n00[2], n01[2], n10[2], n11[2];
        floatx4 nw;
        if (tap < 8)
            stage(tap + 1, n00, n01, n10, n11, nw);

        // pin: nothing below may be hoisted above, nothing above may sink below.
        // This forces the gathers to be ISSUED here, staying in flight across
        // the interp+MFMA window instead of being sunk to their uses.
        __builtin_amdgcn_sched_barrier(0);

        // (3) interp current raws -> B fragments (waits only on the oldest loads,
        //     i.e. the previous iteration's gathers)
        bf16x8 bfrag[2];
#pragma unroll
        for (int kc = 0; kc < 2; kc++) {
            int4 r;
            r.x = interp_word(c00[kc].x, c01[kc].x, c10[kc].x, c11[kc].x,
                              cw[0], cw[1], cw[2], cw[3]);
            r.y = interp_word(c00[kc].y, c01[kc].y, c10[kc].y, c11[kc].y,
                              cw[0], cw[1], cw[2], cw[3]);
            r.z = interp_word(c00[kc].z, c01[kc].z, c10[kc].z, c11[kc].z,
                              cw[0], cw[1], cw[2], cw[3]);
            r.w = interp_word(c00[kc].w, c01[kc].w, c10[kc].w, c11[kc].w,
                              cw[0], cw[1], cw[2], cw[3]);
            bfrag[kc] = __builtin_bit_cast(bf16x8, r);
        }

        // (4) MFMAs (vmcnt waits cover af[] only; gathers remain outstanding)
#pragma unroll
        for (int mt = 0; mt < 8; mt++)
            acc[mt] = __builtin_amdgcn_mfma_f32_16x16x32_bf16(af[mt * 2], bfrag[0], acc[mt], 0, 0, 0);
#pragma unroll
        for (int mt = 0; mt < 8; mt++)
            acc[mt] = __builtin_amdgcn_mfma_f32_16x16x32_bf16(af[mt * 2 + 1], bfrag[1], acc[mt], 0, 0, 0);

        // (5) rotate pipeline registers
        if (tap < 8) {
#pragma unroll
            for (int kc = 0; kc < 2; kc++) {
                c00[kc] = n00[kc]; c01[kc] = n01[kc];
                c10[kc] = n10[kc]; c11[kc] = n11[kc];
            }
            cw = nw;
        }
    }

    // --- epilogue: D col=frow (px), row=quad*4+rg (oc) ---
    float* outb = out + (size_t)b * 524288 + px;
#pragma unroll
    for (int mt = 0; mt < 8; mt++) {
        float4 bc = *(const float4*)(bias + mt * 16 + quad * 4);
        float bcv[4] = {bc.x, bc.y, bc.z, bc.w};
#pragma unroll
        for (int rg = 0; rg < 4; rg++) {
            int oc = mt * 16 + quad * 4 + rg;
            outb[oc * 4096] = acc[mt][rg] + bcv[rg];
        }
    }
}

extern "C" void kernel_launch(void* const* d_in, const int* in_sizes, int n_in,
                              void* d_out, int out_size, void* d_ws, size_t ws_size,
                              hipStream_t stream) {
    const float* x    = (const float*)d_in[0];
    const float* Woff = (const float*)d_in[1];
    const float* boff = (const float*)d_in[2];
    const float* Wk   = (const float*)d_in[3];
    const float* bk   = (const float*)d_in[4];
    float* out = (float*)d_out;

    char* ws = (char*)d_ws;
    unsigned short* xt    = (unsigned short*)ws;               // 8388608 B
    unsigned short* Wkb2  = (unsigned short*)(ws + 8388608);   // 147456 B
    unsigned short* Woffb = (unsigned short*)(ws + 8536064);   // 36864 B

    prep_all<<<1384, 256, 0, stream>>>(x, Wk, Woff, xt, Wkb2, Woffb);
    fused_kernel<<<4096, 64, 0, stream>>>(xt, Wkb2, Woffb, boff, bk, out);
}

// Round 5
// 134.246 us; speedup vs baseline: 1.3302x; 1.3302x over previous
//
#include <hip/hip_runtime.h>

typedef __attribute__((ext_vector_type(8))) short bf16x8;
typedef __attribute__((ext_vector_type(4))) float floatx4;

__device__ __forceinline__ unsigned short f2bf(float f) {
    unsigned int u = __float_as_uint(f);
    u += 0x7FFFu + ((u >> 16) & 1u);
    return (unsigned short)(u >> 16);
}

__device__ __forceinline__ int interp_word(int a00, int a01, int a10, int a11,
                                           float w00, float w01, float w10, float w11) {
    float vl = w00 * __uint_as_float((unsigned)a00 << 16)
             + w01 * __uint_as_float((unsigned)a01 << 16)
             + w10 * __uint_as_float((unsigned)a10 << 16)
             + w11 * __uint_as_float((unsigned)a11 << 16);
    float vh = w00 * __uint_as_float((unsigned)a00 & 0xffff0000u)
             + w01 * __uint_as_float((unsigned)a01 & 0xffff0000u)
             + w10 * __uint_as_float((unsigned)a10 & 0xffff0000u)
             + w11 * __uint_as_float((unsigned)a11 & 0xffff0000u);
    return (int)__builtin_amdgcn_perm(__float_as_uint(vh) + 0x8000u,
                                      __float_as_uint(vl) + 0x8000u, 0x07060302u);
}

// async 16B-per-lane global->LDS (no VGPR round trip). LDS base is wave-uniform;
// HW writes base + lane*16.
__device__ __forceinline__ void g2l16(const unsigned short* g, unsigned short* l) {
    __builtin_amdgcn_global_load_lds(
        (const __attribute__((address_space(1))) unsigned int*)g,
        (__attribute__((address_space(3))) unsigned int*)l, 16, 0, 0);
}

// ---- prep: [0,1024) x->NHWC bf16 | [1024,1312) Wk frag-major | [1312,1384) Woff frag-major ----
// Fragment-major: elem (tap, tile=mt*2+kc, lane, j) at flat [tap*T + tile*512 + lane*8 + j],
// holding W[row = mt*16 + (lane&15)][k = kc*32 + (lane>>4)*8 + j] for that tap.
__global__ __launch_bounds__(256) void prep_all(const float* __restrict__ x,
        const float* __restrict__ Wk, const float* __restrict__ Woff,
        unsigned short* __restrict__ xt, unsigned short* __restrict__ Wkb2,
        unsigned short* __restrict__ Woffb) {
    int bb = blockIdx.x;
    if (bb < 1024) {
        __shared__ float tile[64][65];
        int b = bb >> 6, y = bb & 63;
        const float* src = x + (size_t)b * 262144 + y * 64;   // + c*4096 + xc
        int tx = threadIdx.x & 15, tg = threadIdx.x >> 4;
#pragma unroll
        for (int i = 0; i < 4; i++) {
            int c = tg + i * 16;
            float4 v = *(const float4*)(src + (size_t)c * 4096 + tx * 4);
            tile[c][tx * 4 + 0] = v.x; tile[c][tx * 4 + 1] = v.y;
            tile[c][tx * 4 + 2] = v.z; tile[c][tx * 4 + 3] = v.w;
        }
        __syncthreads();
        unsigned short* dst = xt + (size_t)bb * 4096;   // [xc][c] bf16
#pragma unroll
        for (int i = 0; i < 4; i++) {
            int xc = tg + i * 16;
            int c4 = tx * 4;
            ushort4 v;
            v.x = f2bf(tile[c4 + 0][xc]); v.y = f2bf(tile[c4 + 1][xc]);
            v.z = f2bf(tile[c4 + 2][xc]); v.w = f2bf(tile[c4 + 3][xc]);
            *(ushort4*)(dst + xc * 64 + c4) = v;
        }
    } else if (bb < 1312) {
        int idx = (bb - 1024) * 256 + threadIdx.x;      // [0, 73728): 9 taps x 16 tiles x 512
        int tap = idx >> 13;
        int r = idx & 8191;
        int tile = r >> 9;
        int ln = (r >> 3) & 63;
        int j = r & 7;
        int mt = tile >> 1, kc = tile & 1;
        int oc = mt * 16 + (ln & 15);
        int c = kc * 32 + (ln >> 4) * 8 + j;
        Wkb2[idx] = f2bf(Wk[(oc * 64 + c) * 9 + tap]);
    } else {
        int idx = (bb - 1312) * 256 + threadIdx.x;      // [0, 18432): 9 taps x 4 tiles x 512
        int tap = idx >> 11;
        int r = idx & 2047;
        int tile = r >> 9;
        int ln = (r >> 3) & 63;
        int j = r & 7;
        int mt = tile >> 1, kc = tile & 1;
        int n = mt * 16 + (ln & 15);
        int c = kc * 32 + (ln >> 4) * 8 + j;
        float v = (n < 18) ? Woff[(n * 64 + c) * 9 + tap] : 0.f;
        Woffb[idx] = f2bf(v);
    }
}

// ---- fused kernel: GEMM1 direct-global A (no barrier) -> wave-private offs ->
//      GEMM2 with counted-vmcnt pipeline (guide T3/T4):
//        per tap: {asm vmcnt(8); s_barrier} -> stage A(t+1) via global_load_lds
//        -> issue 8 gathers(t+1) -> interp(t) -> ds_read A(t) + 16 MFMA.
//      A-path is lgkmcnt (LDS), so MFMA waits never drain the vmcnt gathers;
//      gathers get a full-tap latency window and survive the raw s_barrier.
//      As0/As1 are distinct arrays (hand 2x unroll) so ds_reads provably don't
//      alias the in-flight DMA buffer. Regs ~140 < 168 cap (launch_bounds 256,3).
__global__ __launch_bounds__(256, 3) void fused_kernel(
        const unsigned short* __restrict__ xt,     // [b][y][x][c] bf16
        const unsigned short* __restrict__ Wkb2,   // frag-major, 9*8192
        const unsigned short* __restrict__ Woffb,  // frag-major, 9*2048
        const float* __restrict__ boff,
        const float* __restrict__ bias,
        float* __restrict__ out) {
    __shared__ unsigned short As0[8192];           // 16 KB
    __shared__ unsigned short As1[8192];           // 16 KB
    __shared__ float offs[64][20];                 // 5 KB
    int tid = threadIdx.x;
    int wave = tid >> 6, lane = tid & 63;
    int frow = lane & 15, quad = lane >> 4;
    // XCD-aware remap: 2 whole batch images per XCD
    int bb = blockIdx.x;
    int xcd = bb & 7, idx = bb >> 3;
    int b = xcd * 2 + (idx >> 6);
    int pxBase = (idx & 63) * 64;
    int pl = wave * 16 + frow;                     // block-local pixel
    int px = pxBase + pl;
    int y = px >> 6, xx = px & 63;
    const char* img = (const char*)(xt + (size_t)b * 262144) + quad * 16;

    // boff values this lane will need for its offs-write
    float bv[2][4];
#pragma unroll
    for (int mt = 0; mt < 2; mt++)
#pragma unroll
        for (int rg = 0; rg < 4; rg++) {
            int n = mt * 16 + quad * 4 + rg;
            bv[mt][rg] = (n < 18) ? boff[n] : 0.f;
        }

    // ================= GEMM1: offset conv (zero-padded taps), direct-global A ====
    floatx4 acc1[2];
    acc1[0] = (floatx4)(0.f); acc1[1] = (floatx4)(0.f);
#pragma unroll
    for (int tap = 0; tap < 9; tap++) {
        int ry = y + tap / 3 - 1, rx = xx + tap % 3 - 1;
        bool valid = (ry >= 0) & (ry < 64) & (rx >= 0) & (rx < 64);
        const char* src = img + ((ry * 64 + rx) << 7);
        const unsigned short* wofft = Woffb + tap * 2048 + lane * 8;
        bf16x8 bz = {};
#pragma unroll
        for (int kc = 0; kc < 2; kc++) {
            bf16x8 bfr = valid ? *(const bf16x8*)(src + kc * 64) : bz;
#pragma unroll
            for (int mt = 0; mt < 2; mt++) {
                bf16x8 af = *(const bf16x8*)(wofft + (mt * 2 + kc) * 512);
                acc1[mt] = __builtin_amdgcn_mfma_f32_16x16x32_bf16(af, bfr, acc1[mt], 0, 0, 0);
            }
        }
    }
    // offs is WAVE-PRIVATE (writers and readers of row pl are the same wave) -> no barrier.
#pragma unroll
    for (int mt = 0; mt < 2; mt++)
#pragma unroll
        for (int rg = 0; rg < 4; rg++) {
            int n = mt * 16 + quad * 4 + rg;
            if (n < 18) offs[pl][n] = acc1[mt][rg] + bv[mt][rg];
        }

    // ================= GEMM2: counted-vmcnt pipelined tap loop =================
    floatx4 acc[8];
#pragma unroll
    for (int i = 0; i < 8; i++) acc[i] = (floatx4)(0.f);

    const float* op = &offs[pl][0];

    // issue the 8 scattered corner loads + bilinear weights for a tap
    auto stage = [&](int tap, int4 (&r00)[2], int4 (&r01)[2], int4 (&r10)[2],
                     int4 (&r11)[2], floatx4& w) {
        float orow = op[tap];
        float ocol = op[9 + tap];
        float pr = (float)(y + tap / 3 - 1) + orow;
        float pc = (float)(xx + tap % 3 - 1) + ocol;
        pr = fminf(fmaxf(pr, 0.f), 63.f);
        pc = fminf(fmaxf(pc, 0.f), 63.f);
        float fr = floorf(pr), fc = floorf(pc);
        float tr = pr - fr, tc = pc - fc;
        int r0 = (int)fr, c0 = (int)fc;
        int r1 = min(r0 + 1, 63), c1 = min(c0 + 1, 63);
        w[0] = (1.f - tr) * (1.f - tc);
        w[1] = (1.f - tr) * tc;
        w[2] = tr * (1.f - tc);
        w[3] = tr * tc;
        const char* p00 = img + ((r0 * 64 + c0) << 7);
        const char* p01 = img + ((r0 * 64 + c1) << 7);
        const char* p10 = img + ((r1 * 64 + c0) << 7);
        const char* p11 = img + ((r1 * 64 + c1) << 7);
#pragma unroll
        for (int kc = 0; kc < 2; kc++) {
            r00[kc] = *(const int4*)(p00 + kc * 64);
            r01[kc] = *(const int4*)(p01 + kc * 64);
            r10[kc] = *(const int4*)(p10 + kc * 64);
            r11[kc] = *(const int4*)(p11 + kc * 64);
        }
    };

    auto makeB = [&](int4 (&a00)[2], int4 (&a01)[2], int4 (&a10)[2], int4 (&a11)[2],
                     floatx4& w, bf16x8& b0, bf16x8& b1) {
#pragma unroll
        for (int kc = 0; kc < 2; kc++) {
            int4 r;
            r.x = interp_word(a00[kc].x, a01[kc].x, a10[kc].x, a11[kc].x, w[0], w[1], w[2], w[3]);
            r.y = interp_word(a00[kc].y, a01[kc].y, a10[kc].y, a11[kc].y, w[0], w[1], w[2], w[3]);
            r.z = interp_word(a00[kc].z, a01[kc].z, a10[kc].z, a11[kc].z, w[0], w[1], w[2], w[3]);
            r.w = interp_word(a00[kc].w, a01[kc].w, a10[kc].w, a11[kc].w, w[0], w[1], w[2], w[3]);
            if (kc == 0) b0 = __builtin_bit_cast(bf16x8, r);
            else         b1 = __builtin_bit_cast(bf16x8, r);
        }
    };

    int4 c00[2], c01[2], c10[2], c11[2];
    int4 n00[2], n01[2], n10[2], n11[2];
    floatx4 cw, nw;

    // Each wave stages its 2048-short quarter of one tap (4 x 1KB DMA issues).
#define STAGE_A(BUF, TAP) do {                                                 \
        const unsigned short* gs_ = Wkb2 + (TAP) * 8192 + wave * 2048 + lane * 8; \
        g2l16(gs_,         &BUF[wave * 2048]);                                 \
        g2l16(gs_ + 512,   &BUF[wave * 2048 + 512]);                           \
        g2l16(gs_ + 1024,  &BUF[wave * 2048 + 1024]);                          \
        g2l16(gs_ + 1536,  &BUF[wave * 2048 + 1536]);                          \
    } while (0)

    // Per-tap body. Issue order (pinned): [wait S(t), keep G(t); barrier] ->
    // S(t+1) DMA -> G(t+1) gathers -> interp(t) -> ds_read A(t) + MFMA.
#define BODY(TAP, RBUF, WBUF, LAST) do {                                       \
        asm volatile("s_waitcnt vmcnt(8)\n\ts_barrier" ::: "memory");          \
        if (!(LAST)) { STAGE_A(WBUF, (TAP) + 1); }                             \
        __builtin_amdgcn_sched_barrier(0);                                     \
        if (!(LAST)) stage((TAP) + 1, n00, n01, n10, n11, nw);                 \
        __builtin_amdgcn_sched_barrier(0);                                     \
        bf16x8 bf0, bf1;                                                       \
        makeB(c00, c01, c10, c11, cw, bf0, bf1);                               \
        _Pragma("unroll")                                                      \
        for (int mt = 0; mt < 8; mt++) {                                       \
            bf16x8 af = *(const bf16x8*)&RBUF[(mt * 2) * 512 + lane * 8];      \
            acc[mt] = __builtin_amdgcn_mfma_f32_16x16x32_bf16(af, bf0, acc[mt], 0, 0, 0); \
        }                                                                      \
        _Pragma("unroll")                                                      \
        for (int mt = 0; mt < 8; mt++) {                                       \
            bf16x8 af = *(const bf16x8*)&RBUF[(mt * 2 + 1) * 512 + lane * 8];  \
            acc[mt] = __builtin_amdgcn_mfma_f32_16x16x32_bf16(af, bf1, acc[mt], 0, 0, 0); \
        }                                                                      \
        if (!(LAST)) {                                                         \
            _Pragma("unroll")                                                  \
            for (int kc = 0; kc < 2; kc++) {                                   \
                c00[kc] = n00[kc]; c01[kc] = n01[kc];                          \
                c10[kc] = n10[kc]; c11[kc] = n11[kc];                          \
            }                                                                  \
            cw = nw;                                                           \
        }                                                                      \
    } while (0)

    // prologue: pin GEMM1 vmem strictly earlier, then S(0) before G(0)
    __builtin_amdgcn_sched_barrier(0);
    STAGE_A(As0, 0);
    __builtin_amdgcn_sched_barrier(0);
    stage(0, c00, c01, c10, c11, cw);

#pragma unroll 1
    for (int t2 = 0; t2 < 4; t2++) {
        int tap = t2 * 2;
        BODY(tap,     As0, As1, false);
        BODY(tap + 1, As1, As0, false);
    }
    BODY(8, As0, As1, true);

#undef BODY
#undef STAGE_A

    // --- epilogue: D col=frow (px), row=quad*4+rg (oc) ---
    float* outb = out + (size_t)b * 524288 + px;
#pragma unroll
    for (int mt = 0; mt < 8; mt++) {
        float4 bc = *(const float4*)(bias + mt * 16 + quad * 4);
        float bcv[4] = {bc.x, bc.y, bc.z, bc.w};
#pragma unroll
        for (int rg = 0; rg < 4; rg++) {
            int oc = mt * 16 + quad * 4 + rg;
            outb[oc * 4096] = acc[mt][rg] + bcv[rg];
        }
    }
}

extern "C" void kernel_launch(void* const* d_in, const int* in_sizes, int n_in,
                              void* d_out, int out_size, void* d_ws, size_t ws_size,
                              hipStream_t stream) {
    const float* x    = (const float*)d_in[0];
    const float* Woff = (const float*)d_in[1];
    const float* boff = (const float*)d_in[2];
    const float* Wk   = (const float*)d_in[3];
    const float* bk   = (const float*)d_in[4];
    float* out = (float*)d_out;

    char* ws = (char*)d_ws;
    unsigned short* xt    = (unsigned short*)ws;               // 8388608 B
    unsigned short* Wkb2  = (unsigned short*)(ws + 8388608);   // 147456 B
    unsigned short* Woffb = (unsigned short*)(ws + 8536064);   // 36864 B

    prep_all<<<1384, 256, 0, stream>>>(x, Wk, Woff, xt, Wkb2, Woffb);
    fused_kernel<<<1024, 256, 0, stream>>>(xt, Wkb2, Woffb, boff, bk, out);
}